// Round 4
// baseline (102.889 us; speedup 1.0000x reference)
//
#include <hip/hip_runtime.h>

#define N_POINTS  131072
#define N_ANCHORS 2048
#define CHUNKS    16
#define M_PER     (N_ANCHORS / CHUNKS)   // 128 anchors per block
#define THREADS   256
#define PTS       4                      // points per thread
#define PT_STRIDE (N_POINTS / PTS)       // 32768
#define LOG2E     1.4426950408889634f

typedef float v2f __attribute__((ext_vector_type(2)));

// Per-anchor folded constants, every value DUPLICATED so each lives in an
// even-aligned SGPR pair usable directly as the scalar source of
// v_pk_fma_f32 (VOP3P f32 sources are 64-bit; a lone 32-bit SGPR cannot
// broadcast). 64-B aligned for clean s_load_dwordx8/x4.
//   arg(n,m) = q + r.x_n + sp*|x_n|^2 ;  K = exp2(arg) ; out += cf*K
struct __align__(64) Anchor {
    v2f r0, r1, r2, q, sp, cf;   // 48 B used
    v2f pad0, pad1;              // pad to 64 B
};

__global__ void precompute_anchors(const float* __restrict__ aloc,
                                   const float* __restrict__ coeffs,
                                   const float* __restrict__ params,
                                   Anchor* __restrict__ A) {
    int m = blockIdx.x * blockDim.x + threadIdx.x;
    if (m >= N_ANCHORS) return;
    const float a0 = aloc[3 * m + 0];
    const float a1 = aloc[3 * m + 1];
    const float a2 = aloc[3 * m + 2];
    const float w  = params[m];
    const float sp = -(0.5f * LOG2E) / (w * w);
    const float r0 = -2.0f * sp * a0;
    const float r1 = -2.0f * sp * a1;
    const float r2 = -2.0f * sp * a2;
    const float q  = sp * (a0 * a0 + a1 * a1 + a2 * a2);
    const float cf = coeffs[m];
    Anchor out;
    out.r0 = (v2f){r0, r0};  out.r1 = (v2f){r1, r1};
    out.r2 = (v2f){r2, r2};  out.q  = (v2f){q, q};
    out.sp = (v2f){sp, sp};  out.cf = (v2f){cf, cf};
    out.pad0 = (v2f){0.f, 0.f}; out.pad1 = (v2f){0.f, 0.f};
    A[m] = out;
}

// ---------------------------------------------------------------------------
// Grid (128, 16) x 256. 2048 blocks = 8 waves/SIMD. No LDS.
// Anchor constants arrive via thread-invariant loads -> s_load (scalar pipe),
// feeding v_pk_fma_f32 directly from SGPR pairs. 4 points/thread in 2 v2f.
// ---------------------------------------------------------------------------
__global__ __launch_bounds__(256, 8) void linear_potential_main(
    const float* __restrict__ xloc,
    const Anchor* __restrict__ anchors,
    float* __restrict__ out)
{
    const int t   = threadIdx.x;
    const int tid = blockIdx.x * THREADS + t;     // [0, 32768)
    const int n0 = tid;
    const int n1 = tid + PT_STRIDE;
    const int n2 = tid + 2 * PT_STRIDE;
    const int n3 = tid + 3 * PT_STRIDE;

    const v2f xa = { xloc[3 * n0 + 0], xloc[3 * n1 + 0] };
    const v2f ya = { xloc[3 * n0 + 1], xloc[3 * n1 + 1] };
    const v2f za = { xloc[3 * n0 + 2], xloc[3 * n1 + 2] };
    const v2f xb = { xloc[3 * n2 + 0], xloc[3 * n3 + 0] };
    const v2f yb = { xloc[3 * n2 + 1], xloc[3 * n3 + 1] };
    const v2f zb = { xloc[3 * n2 + 2], xloc[3 * n3 + 2] };

    const v2f ssa = __builtin_elementwise_fma(xa, xa,
                    __builtin_elementwise_fma(ya, ya, za * za));
    const v2f ssb = __builtin_elementwise_fma(xb, xb,
                    __builtin_elementwise_fma(yb, yb, zb * zb));

    v2f acca = { 0.0f, 0.0f };
    v2f accb = { 0.0f, 0.0f };

    const Anchor* __restrict__ ach = anchors + blockIdx.y * M_PER;

    #pragma unroll 4
    for (int mm = 0; mm < M_PER; ++mm) {
        const v2f r0 = ach[mm].r0;
        const v2f r1 = ach[mm].r1;
        const v2f r2 = ach[mm].r2;
        const v2f q  = ach[mm].q;
        const v2f sp = ach[mm].sp;
        const v2f cf = ach[mm].cf;

        v2f arga = __builtin_elementwise_fma(sp, ssa, q);
        arga     = __builtin_elementwise_fma(r0, xa, arga);
        arga     = __builtin_elementwise_fma(r1, ya, arga);
        arga     = __builtin_elementwise_fma(r2, za, arga);

        v2f argb = __builtin_elementwise_fma(sp, ssb, q);
        argb     = __builtin_elementwise_fma(r0, xb, argb);
        argb     = __builtin_elementwise_fma(r1, yb, argb);
        argb     = __builtin_elementwise_fma(r2, zb, argb);

        v2f ea = { __builtin_amdgcn_exp2f(arga.x), __builtin_amdgcn_exp2f(arga.y) };
        v2f eb = { __builtin_amdgcn_exp2f(argb.x), __builtin_amdgcn_exp2f(argb.y) };

        acca = __builtin_elementwise_fma(cf, ea, acca);
        accb = __builtin_elementwise_fma(cf, eb, accb);
    }

    atomicAdd(&out[n0], acca.x);
    atomicAdd(&out[n1], acca.y);
    atomicAdd(&out[n2], accb.x);
    atomicAdd(&out[n3], accb.y);
}

extern "C" void kernel_launch(void* const* d_in, const int* in_sizes, int n_in,
                              void* d_out, int out_size, void* d_ws, size_t ws_size,
                              hipStream_t stream) {
    const float* xloc   = (const float*)d_in[0];   // [131072,3]
    const float* aloc   = (const float*)d_in[1];   // [2048,3]
    const float* coeffs = (const float*)d_in[2];   // [2048]
    const float* params = (const float*)d_in[3];   // [2048]
    float* out = (float*)d_out;                    // [131072] f32

    Anchor* A = (Anchor*)d_ws;                     // 2048 * 64 B = 128 KiB

    // d_out is poisoned 0xAA before every timed call -> zero it (capturable).
    hipMemsetAsync(d_out, 0, N_POINTS * sizeof(float), stream);

    precompute_anchors<<<dim3(N_ANCHORS / 256), dim3(256), 0, stream>>>(
        aloc, coeffs, params, A);

    linear_potential_main<<<dim3(N_POINTS / (THREADS * PTS), CHUNKS),
                            dim3(THREADS), 0, stream>>>(
        xloc, A, out);
}